// Round 10
// baseline (462.155 us; speedup 1.0000x reference)
//
#include <hip/hip_runtime.h>
#include <hip/hip_fp16.h>

typedef __attribute__((ext_vector_type(8))) short short8;
typedef __attribute__((ext_vector_type(4))) float floatx4;
typedef __attribute__((ext_vector_type(4))) unsigned int uintx4;
typedef __attribute__((ext_vector_type(2))) unsigned int uintx2;
typedef __attribute__((ext_vector_type(4))) int intx4;
typedef __attribute__((ext_vector_type(4))) unsigned short ushortx4;
typedef unsigned int u32;

#define NN 8192
#define KIN 512
#define COUT 256
#define SHIFT 16.0f

#define AS1 __attribute__((address_space(1)))
#define AS3 __attribute__((address_space(3)))

// async global->LDS, 16B per lane; LDS base wave-uniform, lane lands at +lane*16
__device__ __forceinline__ void stage16(const void* g, void* l) {
  __builtin_amdgcn_global_load_lds((const AS1 u32*)g, (AS3 u32*)l, 16, 0, 0);
}

// ---------- helpers ----------
__device__ __forceinline__ unsigned int f2bf(float f) {
  unsigned int u = __float_as_uint(f);
  return (u + 0x7FFFu + ((u >> 16) & 1u)) >> 16;  // RNE round to bf16
}

// pack two fp32 -> bf16 pair (round-half-up + byte-perm; p>=0, never NaN here)
__device__ __forceinline__ u32 pkbf(float lo, float hi) {
  u32 a = __float_as_uint(lo) + 0x8000u;
  u32 b = __float_as_uint(hi) + 0x8000u;
  return __builtin_amdgcn_perm(b, a, 0x07060302u);  // [hi.b3 hi.b2 lo.b3 lo.b2]
}

__device__ __forceinline__ short8 pack8(const float* p) {
  uintx4 w;
  w.x = pkbf(p[0], p[1]);
  w.y = pkbf(p[2], p[3]);
  w.z = pkbf(p[4], p[5]);
  w.w = pkbf(p[6], p[7]);
  union { uintx4 u; short8 s; } cv; cv.u = w;
  return cv.s;
}

// ---------- K1a: cast input fp32 -> bf16 (coalesced float4 reads) ----------
__global__ void k_cast_input(const float* __restrict__ in, ushortx4* __restrict__ out) {
  int idx = blockIdx.x * 256 + threadIdx.x;
  floatx4 v = ((const floatx4*)in)[idx];
  ushortx4 o;
  o.x = (unsigned short)f2bf(v.x);
  o.y = (unsigned short)f2bf(v.y);
  o.z = (unsigned short)f2bf(v.z);
  o.w = (unsigned short)f2bf(v.w);
  out[idx] = o;
}

// ---------- K1b: weights [512][256] fp32 -> wt [256][512] bf16 (transposed) ----------
__global__ void k_prep_w(const float* __restrict__ w, unsigned short* __restrict__ wt) {
  int idx = blockIdx.x * 256 + threadIdx.x;
  int k = idx >> 8, c = idx & 255;
  wt[c * KIN + k] = (unsigned short)f2bf(w[idx]);
}

// ---------- K2: h = X*W via MFMA; emit ht, e1/e2 (raw) and factored-exp tables ----------
// A1=exp(e1-8), A2=exp(0.25e1-8); e2pk = bf16(exp(e2-8))<<16 | bf16(exp(0.25e2-8))
__global__ __launch_bounds__(256)
void k_gemm_h(const unsigned short* __restrict__ inA, const unsigned short* __restrict__ wt,
              const float* __restrict__ a1, const float* __restrict__ a2,
              unsigned short* __restrict__ ht, float* __restrict__ e1, float* __restrict__ e2,
              float* __restrict__ A1, float* __restrict__ A2, u32* __restrict__ e2pk) {
  int wave = threadIdx.x >> 6;
  int lane = threadIdx.x & 63;
  int n = lane & 15, q = lane >> 4;
  int row0 = blockIdx.x * 64 + wave * 16;
  int mrow = row0 + n;

  floatx4 acc[16];
#pragma unroll
  for (int t = 0; t < 16; ++t) acc[t] = (floatx4){0.f, 0.f, 0.f, 0.f};

  for (int kc = 0; kc < KIN / 32; ++kc) {
    int k0 = kc * 32 + q * 8;
    short8 a = *(const short8*)(inA + (size_t)mrow * KIN + k0);
#pragma unroll
    for (int nt = 0; nt < 16; ++nt) {
      short8 b = *(const short8*)(wt + (size_t)(nt * 16 + n) * KIN + k0);
      acc[nt] = __builtin_amdgcn_mfma_f32_16x16x32_bf16(a, b, acc[nt], 0, 0, 0);
    }
  }

  int i0 = row0 + q * 4;
#pragma unroll
  for (int nt = 0; nt < 16; ++nt) {
    int c = nt * 16 + n;
    uintx2 pk;
    pk.x = f2bf(acc[nt][0]) | (f2bf(acc[nt][1]) << 16);
    pk.y = f2bf(acc[nt][2]) | (f2bf(acc[nt][3]) << 16);
    *(uintx2*)(ht + (size_t)c * NN + i0) = pk;
  }

  float s1[4] = {0.f, 0.f, 0.f, 0.f}, s2[4] = {0.f, 0.f, 0.f, 0.f};
#pragma unroll
  for (int nt = 0; nt < 16; ++nt) {
    float w1 = a1[nt * 16 + n];
    float w2 = a2[nt * 16 + n];
#pragma unroll
    for (int r = 0; r < 4; ++r) {
      s1[r] += acc[nt][r] * w1;
      s2[r] += acc[nt][r] * w2;
    }
  }
#pragma unroll
  for (int m = 1; m < 16; m <<= 1) {
#pragma unroll
    for (int r = 0; r < 4; ++r) {
      s1[r] += __shfl_xor(s1[r], m);
      s2[r] += __shfl_xor(s2[r], m);
    }
  }
  if (n == 0) {
#pragma unroll
    for (int r = 0; r < 4; ++r) {
      float v1 = s1[r], v2 = s2[r];
      e1[i0 + r] = v1;
      e2[i0 + r] = v2;
      A1[i0 + r] = __expf(v1 - 8.0f);
      A2[i0 + r] = __expf(0.25f * v1 - 8.0f);
      u32 b1 = f2bf(__expf(v2 - 8.0f));
      u32 b2 = f2bf(__expf(0.25f * v2 - 8.0f));
      e2pk[i0 + r] = (b1 << 16) | b2;
    }
  }
}

// ---------- K4: FUSED attention + PV; 16-row waves for 3 waves/SIMD occupancy ----------
// wave = 16 rows x 256 cols (acc[16] = 68 AGPR, ~158 unified regs -> 3 waves/SIMD).
// block = 4 waves = 64 rows; grid = 128 rowgroups x 8 j-slices = 1024 blocks;
// LDS 52 KB -> 3 blocks/CU = 12 waves/CU (vs 8 before). Staging/vmcnt as R9 (6 items/wave).
__global__ __launch_bounds__(256, 3)
void k_attn_fused(const int* __restrict__ adj, const unsigned short* __restrict__ ht,
                  const float* __restrict__ A1, const float* __restrict__ A2,
                  const u32* __restrict__ e2pk,
                  __half2* __restrict__ oph, float* __restrict__ Dpart) {
  // LDS: ht buf0 16K | ht buf1 16K | adj buf0 8K | adj buf1 8K | e2s 4K = 53248 B
  __shared__ __align__(16) char smem[53248];
  u32* e2s = (u32*)(smem + 49152);

  int b = blockIdx.x;
  int rg = b >> 3, js = b & 7;                       // js = b&7: slice per XCD (L2 locality)
  int wave = threadIdx.x >> 6, lane = threadIdx.x & 63;
  int n = lane & 15, q = lane >> 4;
  int rowblock = rg * 64;
  int rowbase = rowblock + wave * 16;
  int jbeg = js * 1024;

  // packed (B1,B2) slice -> LDS once
  ((uintx4*)e2s)[threadIdx.x] = *(const uintx4*)(e2pk + jbeg + threadIdx.x * 4);

  float A1v = A1[rowbase + n], A2v = A2[rowbase + n];

  floatx4 acc[16];
  floatx4 accd = (floatx4){0.f, 0.f, 0.f, 0.f};
#pragma unroll
  for (int nt = 0; nt < 16; ++nt) acc[nt] = (floatx4){0.f, 0.f, 0.f, 0.f};

  // ones B-fragment (bf16 1.0 pairs) for denominator MFMA
  union { uintx4 u; short8 s; } onesu;
  onesu.u = (uintx4){0x3F803F80u, 0x3F803F80u, 0x3F803F80u, 0x3F803F80u};
  short8 ones = onesu.s;

  // stage chunk ch into buf: 4 ht segs + 2 adj row-groups per wave (6 vm items)
  auto stage = [&](int ch, int buf) {
    int j0g = jbeg + ch * 32;
    char* hbase = smem + buf * 16384;
#pragma unroll
    for (int i = 0; i < 4; ++i) {
      int seg = wave * 256 + i * 64 + lane;
      int c = seg >> 2;
      int j8 = (seg & 3) * 8;
      stage16(ht + (size_t)c * NN + j0g + j8, hbase + (size_t)(wave * 256 + i * 64) * 16);
    }
    char* abase = smem + 32768 + buf * 8192 + wave * 2048;
    const int* aw = adj + (size_t)(rowblock + wave * 16) * NN + j0g;
#pragma unroll
    for (int i = 0; i < 2; ++i) {
      stage16(aw + (size_t)(i * 8 + (lane & 7)) * NN + (lane >> 3) * 4, abase + i * 1024);
    }
  };

  int rlo = n & 7, rhi = n >> 3;

  stage(0, 0);
  // e2s visible to all waves (vmcnt untouched; stage(0) keeps flying)
  asm volatile("s_waitcnt lgkmcnt(0)" ::: "memory");
  asm volatile("s_barrier" ::: "memory");

  for (int ch = 0; ch < 32; ++ch) {
    int cur = ch & 1;
    if (ch < 31) {
      stage(ch + 1, cur ^ 1);                        // 6 newest vm items = next chunk
      asm volatile("s_waitcnt vmcnt(6)" ::: "memory"); // chunk ch (ht+adj) landed, ours
    } else {
      asm volatile("s_waitcnt vmcnt(0)" ::: "memory");
    }

    // ---- p-compute (own-wave adj + LDS e2pk; no barrier needed yet) ----
    const char* ab = smem + 32768 + cur * 8192 + wave * 2048;
    intx4 a0a = *(const intx4*)(ab + rhi * 1024 + q * 256 + rlo * 16);
    intx4 a0b = *(const intx4*)(ab + rhi * 1024 + q * 256 + 128 + rlo * 16);

    uintx4 ba = *(const uintx4*)(e2s + ch * 32 + q * 8);
    uintx4 bb = *(const uintx4*)(e2s + ch * 32 + q * 8 + 4);
    u32 bw[8] = {ba.x, ba.y, ba.z, ba.w, bb.x, bb.y, bb.z, bb.w};

    float p0[8];
#pragma unroll
    for (int jj = 0; jj < 8; ++jj) {
      int av0 = (jj < 4) ? a0a[jj] : a0b[jj - 4];
      float B1 = __uint_as_float(bw[jj] & 0xffff0000u);
      float B2 = __uint_as_float(bw[jj] << 16);
      float pm0 = fmaxf(A1v * B1, A2v * B2);         // = exp(leakyrelu(e1+e2)-16)
      p0[jj] = (av0 != 0) ? pm0 : 0.f;
    }
    short8 af0 = pack8(p0);

    asm volatile("s_barrier" ::: "memory");          // all waves' ht tile landed

    // B-frags from LDS ht tile: frag(t,n,q) at byte t*1024 + n*64 + q*16
    const short8* lb = (const short8*)(smem + (size_t)cur * 16384);
#pragma unroll
    for (int t = 0; t < 16; ++t) {
      short8 bf = lb[t * 64 + n * 4 + q];
      acc[t] = __builtin_amdgcn_mfma_f32_16x16x32_bf16(af0, bf, acc[t], 0, 0, 0);
    }
    accd = __builtin_amdgcn_mfma_f32_16x16x32_bf16(af0, ones, accd, 0, 0, 0);

    // frag reads consumed; buffers reusable. vmcnt (next-chunk DMAs) keeps flying.
    asm volatile("s_waitcnt lgkmcnt(0)" ::: "memory");
    asm volatile("s_barrier" ::: "memory");
  }

  // denominator from accd C-layout: row = q*4+r (any col); lanes n==0 write
  if (n == 0) {
#pragma unroll
    for (int r = 0; r < 4; ++r)
      Dpart[(size_t)js * NN + rowbase + q * 4 + r] = accd[r];
  }

  // numerator partials as half2 row-pairs: word (js*4096 + i/2)*256 + c
  int ibase = rowbase + q * 4;                       // multiple of 4
#pragma unroll
  for (int nt = 0; nt < 16; ++nt) {
    int c = nt * 16 + n;
    oph[((size_t)js * 4096 + (ibase >> 1)) * 256 + c] =
        __floats2half2_rn(acc[nt][0], acc[nt][1]);
    oph[((size_t)js * 4096 + (ibase >> 1) + 1) * 256 + c] =
        __floats2half2_rn(acc[nt][2], acc[nt][3]);
  }
}

// ---------- K5: out = (sum_js oph)/(sum_js Dpart) + bias ----------
__global__ void k_final_part(float* __restrict__ out, const __half2* __restrict__ oph,
                             const float* __restrict__ Dpart, const float* __restrict__ bias) {
  int i = blockIdx.x;
  int c = threadIdx.x;
  int hi = i & 1;
  float s = 0.f, d = 0.f;
#pragma unroll
  for (int js = 0; js < 8; ++js) {
    __half2 h2 = oph[((size_t)js * 4096 + (i >> 1)) * 256 + c];
    s += hi ? __high2float(h2) : __low2float(h2);
    d += Dpart[(size_t)js * NN + i];
  }
  out[(size_t)i * COUT + c] = s / fmaxf(d, 1e-37f) + bias[c];
}

// ---------- Fallback path (atomics, direct adj) if ws is too small ----------
__global__ __launch_bounds__(256, 2)
void k_attn_atomic(const int* __restrict__ adj, const unsigned short* __restrict__ ht,
                   const float* __restrict__ e1, const float* __restrict__ e2,
                   float* __restrict__ out_num, float* __restrict__ Dbuf) {
  int b = blockIdx.x;
  int rg = b >> 3, js = b & 7;
  int wave = threadIdx.x >> 6, lane = threadIdx.x & 63;
  int n = lane & 15, q = lane >> 4;
  int rowbase = rg * 128 + wave * 32;

  float e1v0 = e1[rowbase + n];
  float e1v1 = e1[rowbase + 16 + n];

  floatx4 acc[2][16];
#pragma unroll
  for (int t = 0; t < 2; ++t)
#pragma unroll
    for (int nt = 0; nt < 16; ++nt) acc[t][nt] = (floatx4){0.f, 0.f, 0.f, 0.f};

  float d0 = 0.f, d1 = 0.f;
  int jbeg = js * 1024;

  for (int ch = 0; ch < 32; ++ch) {
    int j0 = jbeg + ch * 32 + q * 8;
    floatx4 ea = *(const floatx4*)(e2 + j0);
    floatx4 eb = *(const floatx4*)(e2 + j0 + 4);
    float ev[8] = {ea.x, ea.y, ea.z, ea.w, eb.x, eb.y, eb.z, eb.w};

    intx4 A00 = *(const intx4*)(adj + (size_t)(rowbase + n) * NN + j0);
    intx4 A01 = *(const intx4*)(adj + (size_t)(rowbase + n) * NN + j0 + 4);
    intx4 A10 = *(const intx4*)(adj + (size_t)(rowbase + 16 + n) * NN + j0);
    intx4 A11 = *(const intx4*)(adj + (size_t)(rowbase + 16 + n) * NN + j0 + 4);

    float p0[8], p1[8];
#pragma unroll
    for (int jj = 0; jj < 8; ++jj) {
      int av0 = (jj < 4) ? A00[jj] : A01[jj - 4];
      int av1 = (jj < 4) ? A10[jj] : A11[jj - 4];
      float t0 = e1v0 + ev[jj];
      float t1 = e1v1 + ev[jj];
      float f0 = fmaxf(t0, 0.25f * t0);
      float f1 = fmaxf(t1, 0.25f * t1);
      float x0 = __expf(f0 - SHIFT);
      float x1 = __expf(f1 - SHIFT);
      p0[jj] = (av0 != 0) ? x0 : 0.f;
      p1[jj] = (av1 != 0) ? x1 : 0.f;
      d0 += p0[jj];
      d1 += p1[jj];
    }
    short8 af0 = pack8(p0);
    short8 af1 = pack8(p1);

#pragma unroll
    for (int g = 0; g < 2; ++g) {
      short8 bf[8];
#pragma unroll
      for (int t = 0; t < 8; ++t)
        bf[t] = *(const short8*)(ht + (size_t)((g * 8 + t) * 16 + n) * NN + j0);
#pragma unroll
      for (int t = 0; t < 8; ++t) {
        acc[0][g * 8 + t] = __builtin_amdgcn_mfma_f32_16x16x32_bf16(af0, bf[t], acc[0][g * 8 + t], 0, 0, 0);
        acc[1][g * 8 + t] = __builtin_amdgcn_mfma_f32_16x16x32_bf16(af1, bf[t], acc[1][g * 8 + t], 0, 0, 0);
      }
    }
  }

  d0 += __shfl_xor(d0, 16); d0 += __shfl_xor(d0, 32);
  d1 += __shfl_xor(d1, 16); d1 += __shfl_xor(d1, 32);
  if (lane < 16) {
    atomicAdd(Dbuf + rowbase + lane, d0);
    atomicAdd(Dbuf + rowbase + 16 + lane, d1);
  }

#pragma unroll
  for (int t2 = 0; t2 < 2; ++t2) {
#pragma unroll
    for (int nt = 0; nt < 16; ++nt) {
#pragma unroll
      for (int r = 0; r < 4; ++r) {
        int i = rowbase + t2 * 16 + q * 4 + r;
        atomicAdd(out_num + (size_t)i * COUT + nt * 16 + n, acc[t2][nt][r]);
      }
    }
  }
}

__global__ void k_final_atomic(float* __restrict__ out, const float* __restrict__ Dbuf,
                               const float* __restrict__ bias) {
  int idx = blockIdx.x * 256 + threadIdx.x;
  int i = idx >> 8, c = idx & 255;
  float d = fmaxf(Dbuf[i], 1e-37f);
  out[idx] = out[idx] / d + bias[c];
}

// ---------- launch ----------
extern "C" void kernel_launch(void* const* d_in, const int* in_sizes, int n_in,
                              void* d_out, int out_size, void* d_ws, size_t ws_size,
                              hipStream_t stream) {
  const float* input   = (const float*)d_in[0];
  const int*   adj     = (const int*)d_in[1];
  const float* weights = (const float*)d_in[2];
  const float* a1      = (const float*)d_in[3];
  const float* a2      = (const float*)d_in[4];
  const float* bias    = (const float*)d_in[5];
  float* out = (float*)d_out;
  char* ws = (char*)d_ws;

  unsigned short* inA = (unsigned short*)(ws);                 // 8 MB   [8192][512] bf16
  unsigned short* wt  = (unsigned short*)(ws + 8388608);       // 256 KB [256][512] bf16
  unsigned short* ht  = (unsigned short*)(ws + 8650752);       // 4 MB   [256][8192] bf16
  float* e1    = (float*)(ws + 12845056);                      // 32 KB
  float* e2    = (float*)(ws + 12877824);                      // 32 KB
  float* A1    = (float*)(ws + 12910592);                      // 32 KB exp(e1-8)
  float* A2    = (float*)(ws + 12943360);                      // 32 KB exp(.25e1-8)
  u32*   e2pk  = (u32*)  (ws + 12976128);                      // 32 KB packed B1|B2
  float* Dpart = (float*)(ws + 13008896);                      // 256 KB [8][8192]
  __half2* oph = (__half2*)(ws + 13271040);                    // 32 MB  [8][4096][256] half2
  const size_t WS_NEEDED_PART = 13271040 + (size_t)8 * NN * COUT * 2;  // ~45 MB
  float* Dbuf = Dpart;

  k_cast_input<<<4096, 256, 0, stream>>>(input, (ushortx4*)inA);
  k_prep_w<<<512, 256, 0, stream>>>(weights, wt);
  k_gemm_h<<<128, 256, 0, stream>>>(inA, wt, a1, a2, ht, e1, e2, A1, A2, e2pk);

  if (ws_size >= WS_NEEDED_PART) {
    k_attn_fused<<<1024, 256, 0, stream>>>(adj, ht, A1, A2, e2pk, oph, Dpart);
    k_final_part<<<8192, 256, 0, stream>>>(out, oph, Dpart, bias);
  } else {
    hipMemsetAsync(out, 0, (size_t)NN * COUT * sizeof(float), stream);
    hipMemsetAsync(Dbuf, 0, NN * sizeof(float), stream);
    k_attn_atomic<<<512, 256, 0, stream>>>(adj, ht, e1, e2, out, Dbuf);
    k_final_atomic<<<8192, 256, 0, stream>>>(out, Dbuf, bias);
  }
}

// Round 11
// 447.407 us; speedup vs baseline: 1.0330x; 1.0330x over previous
//
#include <hip/hip_runtime.h>
#include <hip/hip_fp16.h>

typedef __attribute__((ext_vector_type(8))) short short8;
typedef __attribute__((ext_vector_type(4))) float floatx4;
typedef __attribute__((ext_vector_type(4))) unsigned int uintx4;
typedef __attribute__((ext_vector_type(2))) unsigned int uintx2;
typedef __attribute__((ext_vector_type(4))) int intx4;
typedef __attribute__((ext_vector_type(4))) unsigned short ushortx4;
typedef unsigned int u32;

#define NN 8192
#define KIN 512
#define COUT 256
#define SHIFT 16.0f

#define AS1 __attribute__((address_space(1)))
#define AS3 __attribute__((address_space(3)))

// async global->LDS, 16B per lane; LDS base wave-uniform, lane lands at +lane*16
__device__ __forceinline__ void stage16(const void* g, void* l) {
  __builtin_amdgcn_global_load_lds((const AS1 u32*)g, (AS3 u32*)l, 16, 0, 0);
}

// ---------- helpers ----------
__device__ __forceinline__ unsigned int f2bf(float f) {
  unsigned int u = __float_as_uint(f);
  return (u + 0x7FFFu + ((u >> 16) & 1u)) >> 16;  // RNE round to bf16
}

// pack two fp32 -> bf16 pair (round-half-up + byte-perm; p>=0, never NaN here)
__device__ __forceinline__ u32 pkbf(float lo, float hi) {
  u32 a = __float_as_uint(lo) + 0x8000u;
  u32 b = __float_as_uint(hi) + 0x8000u;
  return __builtin_amdgcn_perm(b, a, 0x07060302u);  // [hi.b3 hi.b2 lo.b3 lo.b2]
}

__device__ __forceinline__ short8 pack8(const float* p) {
  uintx4 w;
  w.x = pkbf(p[0], p[1]);
  w.y = pkbf(p[2], p[3]);
  w.z = pkbf(p[4], p[5]);
  w.w = pkbf(p[6], p[7]);
  union { uintx4 u; short8 s; } cv; cv.u = w;
  return cv.s;
}

// ---------- K1a: cast input fp32 -> bf16 (coalesced float4 reads) ----------
__global__ void k_cast_input(const float* __restrict__ in, ushortx4* __restrict__ out) {
  int idx = blockIdx.x * 256 + threadIdx.x;
  floatx4 v = ((const floatx4*)in)[idx];
  ushortx4 o;
  o.x = (unsigned short)f2bf(v.x);
  o.y = (unsigned short)f2bf(v.y);
  o.z = (unsigned short)f2bf(v.z);
  o.w = (unsigned short)f2bf(v.w);
  out[idx] = o;
}

// ---------- K1b: weights [512][256] fp32 -> wt [256][512] bf16 (transposed) ----------
__global__ void k_prep_w(const float* __restrict__ w, unsigned short* __restrict__ wt) {
  int idx = blockIdx.x * 256 + threadIdx.x;
  int k = idx >> 8, c = idx & 255;
  wt[c * KIN + k] = (unsigned short)f2bf(w[idx]);
}

// ---------- K2: h = X*W via MFMA; emit ht, e1/e2 (raw) and factored-exp tables ----------
// A1=exp(e1-8), A2=exp(0.25e1-8); e2pk = bf16(exp(e2-8))<<16 | bf16(exp(0.25e2-8))
__global__ __launch_bounds__(256)
void k_gemm_h(const unsigned short* __restrict__ inA, const unsigned short* __restrict__ wt,
              const float* __restrict__ a1, const float* __restrict__ a2,
              unsigned short* __restrict__ ht, float* __restrict__ e1, float* __restrict__ e2,
              float* __restrict__ A1, float* __restrict__ A2, u32* __restrict__ e2pk) {
  int wave = threadIdx.x >> 6;
  int lane = threadIdx.x & 63;
  int n = lane & 15, q = lane >> 4;
  int row0 = blockIdx.x * 64 + wave * 16;
  int mrow = row0 + n;

  floatx4 acc[16];
#pragma unroll
  for (int t = 0; t < 16; ++t) acc[t] = (floatx4){0.f, 0.f, 0.f, 0.f};

  for (int kc = 0; kc < KIN / 32; ++kc) {
    int k0 = kc * 32 + q * 8;
    short8 a = *(const short8*)(inA + (size_t)mrow * KIN + k0);
#pragma unroll
    for (int nt = 0; nt < 16; ++nt) {
      short8 b = *(const short8*)(wt + (size_t)(nt * 16 + n) * KIN + k0);
      acc[nt] = __builtin_amdgcn_mfma_f32_16x16x32_bf16(a, b, acc[nt], 0, 0, 0);
    }
  }

  int i0 = row0 + q * 4;
#pragma unroll
  for (int nt = 0; nt < 16; ++nt) {
    int c = nt * 16 + n;
    uintx2 pk;
    pk.x = f2bf(acc[nt][0]) | (f2bf(acc[nt][1]) << 16);
    pk.y = f2bf(acc[nt][2]) | (f2bf(acc[nt][3]) << 16);
    *(uintx2*)(ht + (size_t)c * NN + i0) = pk;
  }

  float s1[4] = {0.f, 0.f, 0.f, 0.f}, s2[4] = {0.f, 0.f, 0.f, 0.f};
#pragma unroll
  for (int nt = 0; nt < 16; ++nt) {
    float w1 = a1[nt * 16 + n];
    float w2 = a2[nt * 16 + n];
#pragma unroll
    for (int r = 0; r < 4; ++r) {
      s1[r] += acc[nt][r] * w1;
      s2[r] += acc[nt][r] * w2;
    }
  }
#pragma unroll
  for (int m = 1; m < 16; m <<= 1) {
#pragma unroll
    for (int r = 0; r < 4; ++r) {
      s1[r] += __shfl_xor(s1[r], m);
      s2[r] += __shfl_xor(s2[r], m);
    }
  }
  if (n == 0) {
#pragma unroll
    for (int r = 0; r < 4; ++r) {
      float v1 = s1[r], v2 = s2[r];
      e1[i0 + r] = v1;
      e2[i0 + r] = v2;
      A1[i0 + r] = __expf(v1 - 8.0f);
      A2[i0 + r] = __expf(0.25f * v1 - 8.0f);
      u32 b1 = f2bf(__expf(v2 - 8.0f));
      u32 b2 = f2bf(__expf(0.25f * v2 - 8.0f));
      e2pk[i0 + r] = (b1 << 16) | b2;
    }
  }
}

// ---------- K4: FUSED attention + PV; factored exp; fp16 partials ----------
// p = adj ? max(A1_i*B1_j, A2_i*B2_j) : 0  (== exp(leakyrelu(e1+e2)-16), exp monotone)
// Denominator via MFMA vs ones-B fragment. Partials: half2 word layout
// oph[(js*4096 + (i>>1))*256 + c] = (row i_even, row i_even+1).
// 32-row waves / 512 blocks: empirically best (R9=448us; 16-row/1024-block R10=462us
// — per-block ht staging doubles and barrier count doubles; do NOT shrink the tile).
__global__ __launch_bounds__(256, 2)
void k_attn_fused(const int* __restrict__ adj, const unsigned short* __restrict__ ht,
                  const float* __restrict__ A1, const float* __restrict__ A2,
                  const u32* __restrict__ e2pk,
                  __half2* __restrict__ oph, float* __restrict__ Dpart) {
  // LDS: buf0 [ht 16K | adj 16K] buf1 [ht 16K | adj 16K] e2s 4K = 69632 B
  __shared__ __align__(16) char smem[69632];
  u32* e2s = (u32*)(smem + 65536);

  int b = blockIdx.x;
  int rg = b >> 3, js = b & 7;
  int wave = threadIdx.x >> 6, lane = threadIdx.x & 63;
  int n = lane & 15, q = lane >> 4;
  int rowblock = rg * 128;
  int rowbase = rowblock + wave * 32;
  int jbeg = js * 1024;

  // packed (B1,B2) slice -> LDS once
  ((uintx4*)e2s)[threadIdx.x] = *(const uintx4*)(e2pk + jbeg + threadIdx.x * 4);

  float A1v0 = A1[rowbase + n],      A2v0 = A2[rowbase + n];
  float A1v1 = A1[rowbase + 16 + n], A2v1 = A2[rowbase + 16 + n];

  floatx4 acc[2][16];
  floatx4 accd[2];
#pragma unroll
  for (int t = 0; t < 2; ++t) {
    accd[t] = (floatx4){0.f, 0.f, 0.f, 0.f};
#pragma unroll
    for (int nt = 0; nt < 16; ++nt) acc[t][nt] = (floatx4){0.f, 0.f, 0.f, 0.f};
  }

  // ones B-fragment (bf16 1.0 pairs) for denominator MFMA
  union { uintx4 u; short8 s; } onesu;
  onesu.u = (uintx4){0x3F803F80u, 0x3F803F80u, 0x3F803F80u, 0x3F803F80u};
  short8 ones = onesu.s;

  // stage chunk ch into buf: 4 ht segs + 4 adj row-groups per wave (8 vm items)
  auto stage = [&](int ch, int buf) {
    int j0g = jbeg + ch * 32;
    char* hbase = smem + buf * 32768;
#pragma unroll
    for (int i = 0; i < 4; ++i) {
      int seg = wave * 256 + i * 64 + lane;
      int c = seg >> 2;
      int j8 = (seg & 3) * 8;
      stage16(ht + (size_t)c * NN + j0g + j8, hbase + (size_t)(wave * 256 + i * 64) * 16);
    }
    char* abase = hbase + 16384 + wave * 4096;
    const int* aw = adj + (size_t)(rowblock + wave * 32) * NN + j0g;
#pragma unroll
    for (int i = 0; i < 4; ++i) {
      stage16(aw + (size_t)(i * 8 + (lane & 7)) * NN + (lane >> 3) * 4, abase + i * 1024);
    }
  };

  int rlo = n & 7, rhi = n >> 3;

  stage(0, 0);
  // e2s visible to all waves (vmcnt untouched; stage(0) keeps flying)
  asm volatile("s_waitcnt lgkmcnt(0)" ::: "memory");
  asm volatile("s_barrier" ::: "memory");

  for (int ch = 0; ch < 32; ++ch) {
    int cur = ch & 1;
    if (ch < 31) {
      stage(ch + 1, cur ^ 1);                        // 8 newest vm items = next chunk
      asm volatile("s_waitcnt vmcnt(8)" ::: "memory"); // chunk ch (ht+adj) landed, ours
    } else {
      asm volatile("s_waitcnt vmcnt(0)" ::: "memory");
    }

    // ---- p-compute (own-wave adj + LDS e2pk; no barrier needed yet) ----
    const char* ab = smem + cur * 32768 + 16384 + wave * 4096;
    intx4 a0a = *(const intx4*)(ab + rhi * 1024 + q * 256 + rlo * 16);
    intx4 a0b = *(const intx4*)(ab + rhi * 1024 + q * 256 + 128 + rlo * 16);
    intx4 a1a = *(const intx4*)(ab + 2048 + rhi * 1024 + q * 256 + rlo * 16);
    intx4 a1b = *(const intx4*)(ab + 2048 + rhi * 1024 + q * 256 + 128 + rlo * 16);

    uintx4 ba = *(const uintx4*)(e2s + ch * 32 + q * 8);
    uintx4 bb = *(const uintx4*)(e2s + ch * 32 + q * 8 + 4);
    u32 bw[8] = {ba.x, ba.y, ba.z, ba.w, bb.x, bb.y, bb.z, bb.w};

    float p0[8], p1[8];
#pragma unroll
    for (int jj = 0; jj < 8; ++jj) {
      int av0 = (jj < 4) ? a0a[jj] : a0b[jj - 4];
      int av1 = (jj < 4) ? a1a[jj] : a1b[jj - 4];
      float B1 = __uint_as_float(bw[jj] & 0xffff0000u);
      float B2 = __uint_as_float(bw[jj] << 16);
      float m10 = A1v0 * B1, m20 = A2v0 * B2;
      float m11 = A1v1 * B1, m21 = A2v1 * B2;
      float pm0 = fmaxf(m10, m20);                   // = exp(leakyrelu(e1+e2)-16)
      float pm1 = fmaxf(m11, m21);
      p0[jj] = (av0 != 0) ? pm0 : 0.f;
      p1[jj] = (av1 != 0) ? pm1 : 0.f;
    }
    short8 af0 = pack8(p0);
    short8 af1 = pack8(p1);

    asm volatile("s_barrier" ::: "memory");          // all waves' ht tile landed

    // B-frags from LDS ht tile: frag(t,n,q) at byte t*1024 + n*64 + q*16
    const short8* lb = (const short8*)(smem + (size_t)cur * 32768);
#pragma unroll
    for (int t = 0; t < 16; ++t) {
      short8 bf = lb[t * 64 + n * 4 + q];
      acc[0][t] = __builtin_amdgcn_mfma_f32_16x16x32_bf16(af0, bf, acc[0][t], 0, 0, 0);
      acc[1][t] = __builtin_amdgcn_mfma_f32_16x16x32_bf16(af1, bf, acc[1][t], 0, 0, 0);
    }
    accd[0] = __builtin_amdgcn_mfma_f32_16x16x32_bf16(af0, ones, accd[0], 0, 0, 0);
    accd[1] = __builtin_amdgcn_mfma_f32_16x16x32_bf16(af1, ones, accd[1], 0, 0, 0);

    // frag reads consumed; buffers reusable. vmcnt (next-chunk DMAs) keeps flying.
    asm volatile("s_waitcnt lgkmcnt(0)" ::: "memory");
    asm volatile("s_barrier" ::: "memory");
  }

  // denominator from accd C-layout: row = q*4+r (any col); lanes n==0 write
  if (n == 0) {
#pragma unroll
    for (int t2 = 0; t2 < 2; ++t2)
#pragma unroll
      for (int r = 0; r < 4; ++r)
        Dpart[(size_t)js * NN + rowbase + t2 * 16 + q * 4 + r] = accd[t2][r];
  }

  // numerator partials as half2 row-pairs: word (js*4096 + i/2)*256 + c
#pragma unroll
  for (int t2 = 0; t2 < 2; ++t2) {
    int ibase = rowbase + t2 * 16 + q * 4;           // multiple of 4
#pragma unroll
    for (int nt = 0; nt < 16; ++nt) {
      int c = nt * 16 + n;
      oph[((size_t)js * 4096 + (ibase >> 1)) * 256 + c] =
          __floats2half2_rn(acc[t2][nt][0], acc[t2][nt][1]);
      oph[((size_t)js * 4096 + (ibase >> 1) + 1) * 256 + c] =
          __floats2half2_rn(acc[t2][nt][2], acc[t2][nt][3]);
    }
  }
}

// ---------- K5: out = (sum_js oph)/(sum_js Dpart) + bias ----------
__global__ void k_final_part(float* __restrict__ out, const __half2* __restrict__ oph,
                             const float* __restrict__ Dpart, const float* __restrict__ bias) {
  int i = blockIdx.x;
  int c = threadIdx.x;
  int hi = i & 1;
  float s = 0.f, d = 0.f;
#pragma unroll
  for (int js = 0; js < 8; ++js) {
    __half2 h2 = oph[((size_t)js * 4096 + (i >> 1)) * 256 + c];
    s += hi ? __high2float(h2) : __low2float(h2);
    d += Dpart[(size_t)js * NN + i];
  }
  out[(size_t)i * COUT + c] = s / fmaxf(d, 1e-37f) + bias[c];
}

// ---------- Fallback path (atomics, direct adj) if ws is too small ----------
__global__ __launch_bounds__(256, 2)
void k_attn_atomic(const int* __restrict__ adj, const unsigned short* __restrict__ ht,
                   const float* __restrict__ e1, const float* __restrict__ e2,
                   float* __restrict__ out_num, float* __restrict__ Dbuf) {
  int b = blockIdx.x;
  int rg = b >> 3, js = b & 7;
  int wave = threadIdx.x >> 6, lane = threadIdx.x & 63;
  int n = lane & 15, q = lane >> 4;
  int rowbase = rg * 128 + wave * 32;

  float e1v0 = e1[rowbase + n];
  float e1v1 = e1[rowbase + 16 + n];

  floatx4 acc[2][16];
#pragma unroll
  for (int t = 0; t < 2; ++t)
#pragma unroll
    for (int nt = 0; nt < 16; ++nt) acc[t][nt] = (floatx4){0.f, 0.f, 0.f, 0.f};

  float d0 = 0.f, d1 = 0.f;
  int jbeg = js * 1024;

  for (int ch = 0; ch < 32; ++ch) {
    int j0 = jbeg + ch * 32 + q * 8;
    floatx4 ea = *(const floatx4*)(e2 + j0);
    floatx4 eb = *(const floatx4*)(e2 + j0 + 4);
    float ev[8] = {ea.x, ea.y, ea.z, ea.w, eb.x, eb.y, eb.z, eb.w};

    intx4 A00 = *(const intx4*)(adj + (size_t)(rowbase + n) * NN + j0);
    intx4 A01 = *(const intx4*)(adj + (size_t)(rowbase + n) * NN + j0 + 4);
    intx4 A10 = *(const intx4*)(adj + (size_t)(rowbase + 16 + n) * NN + j0);
    intx4 A11 = *(const intx4*)(adj + (size_t)(rowbase + 16 + n) * NN + j0 + 4);

    float p0[8], p1[8];
#pragma unroll
    for (int jj = 0; jj < 8; ++jj) {
      int av0 = (jj < 4) ? A00[jj] : A01[jj - 4];
      int av1 = (jj < 4) ? A10[jj] : A11[jj - 4];
      float t0 = e1v0 + ev[jj];
      float t1 = e1v1 + ev[jj];
      float f0 = fmaxf(t0, 0.25f * t0);
      float f1 = fmaxf(t1, 0.25f * t1);
      float x0 = __expf(f0 - SHIFT);
      float x1 = __expf(f1 - SHIFT);
      p0[jj] = (av0 != 0) ? x0 : 0.f;
      p1[jj] = (av1 != 0) ? x1 : 0.f;
      d0 += p0[jj];
      d1 += p1[jj];
    }
    short8 af0 = pack8(p0);
    short8 af1 = pack8(p1);

#pragma unroll
    for (int g = 0; g < 2; ++g) {
      short8 bf[8];
#pragma unroll
      for (int t = 0; t < 8; ++t)
        bf[t] = *(const short8*)(ht + (size_t)((g * 8 + t) * 16 + n) * NN + j0);
#pragma unroll
      for (int t = 0; t < 8; ++t) {
        acc[0][g * 8 + t] = __builtin_amdgcn_mfma_f32_16x16x32_bf16(af0, bf[t], acc[0][g * 8 + t], 0, 0, 0);
        acc[1][g * 8 + t] = __builtin_amdgcn_mfma_f32_16x16x32_bf16(af1, bf[t], acc[1][g * 8 + t], 0, 0, 0);
      }
    }
  }

  d0 += __shfl_xor(d0, 16); d0 += __shfl_xor(d0, 32);
  d1 += __shfl_xor(d1, 16); d1 += __shfl_xor(d1, 32);
  if (lane < 16) {
    atomicAdd(Dbuf + rowbase + lane, d0);
    atomicAdd(Dbuf + rowbase + 16 + lane, d1);
  }

#pragma unroll
  for (int t2 = 0; t2 < 2; ++t2) {
#pragma unroll
    for (int nt = 0; nt < 16; ++nt) {
#pragma unroll
      for (int r = 0; r < 4; ++r) {
        int i = rowbase + t2 * 16 + q * 4 + r;
        atomicAdd(out_num + (size_t)i * COUT + nt * 16 + n, acc[t2][nt][r]);
      }
    }
  }
}

__global__ void k_final_atomic(float* __restrict__ out, const float* __restrict__ Dbuf,
                               const float* __restrict__ bias) {
  int idx = blockIdx.x * 256 + threadIdx.x;
  int i = idx >> 8, c = idx & 255;
  float d = fmaxf(Dbuf[i], 1e-37f);
  out[idx] = out[idx] / d + bias[c];
}

// ---------- launch ----------
extern "C" void kernel_launch(void* const* d_in, const int* in_sizes, int n_in,
                              void* d_out, int out_size, void* d_ws, size_t ws_size,
                              hipStream_t stream) {
  const float* input   = (const float*)d_in[0];
  const int*   adj     = (const int*)d_in[1];
  const float* weights = (const float*)d_in[2];
  const float* a1      = (const float*)d_in[3];
  const float* a2      = (const float*)d_in[4];
  const float* bias    = (const float*)d_in[5];
  float* out = (float*)d_out;
  char* ws = (char*)d_ws;

  unsigned short* inA = (unsigned short*)(ws);                 // 8 MB   [8192][512] bf16
  unsigned short* wt  = (unsigned short*)(ws + 8388608);       // 256 KB [256][512] bf16
  unsigned short* ht  = (unsigned short*)(ws + 8650752);       // 4 MB   [256][8192] bf16
  float* e1    = (float*)(ws + 12845056);                      // 32 KB
  float* e2    = (float*)(ws + 12877824);                      // 32 KB
  float* A1    = (float*)(ws + 12910592);                      // 32 KB exp(e1-8)
  float* A2    = (float*)(ws + 12943360);                      // 32 KB exp(.25e1-8)
  u32*   e2pk  = (u32*)  (ws + 12976128);                      // 32 KB packed B1|B2
  float* Dpart = (float*)(ws + 13008896);                      // 256 KB [8][8192]
  __half2* oph = (__half2*)(ws + 13271040);                    // 32 MB  [8][4096][256] half2
  const size_t WS_NEEDED_PART = 13271040 + (size_t)8 * NN * COUT * 2;  // ~45 MB
  float* Dbuf = Dpart;

  k_cast_input<<<4096, 256, 0, stream>>>(input, (ushortx4*)inA);
  k_prep_w<<<512, 256, 0, stream>>>(weights, wt);
  k_gemm_h<<<128, 256, 0, stream>>>(inA, wt, a1, a2, ht, e1, e2, A1, A2, e2pk);

  if (ws_size >= WS_NEEDED_PART) {
    k_attn_fused<<<512, 256, 0, stream>>>(adj, ht, A1, A2, e2pk, oph, Dpart);
    k_final_part<<<8192, 256, 0, stream>>>(out, oph, Dpart, bias);
  } else {
    hipMemsetAsync(out, 0, (size_t)NN * COUT * sizeof(float), stream);
    hipMemsetAsync(Dbuf, 0, NN * sizeof(float), stream);
    k_attn_atomic<<<512, 256, 0, stream>>>(adj, ht, e1, e2, out, Dbuf);
    k_final_atomic<<<8192, 256, 0, stream>>>(out, Dbuf, bias);
  }
}